// Round 7
// baseline (659.423 us; speedup 1.0000x reference)
//
#include <hip/hip_runtime.h>
#include <math.h>

#define DMODEL 1024
#define NQKV   3072
#define SEQ    1024
#define NH     16
#define DH     64
#define HS     (SEQ*DH)
constexpr float PI_F   = 3.14159265358979323846f;
constexpr float LOG2E  = 1.44269504088896f;

typedef _Float16 half8   __attribute__((ext_vector_type(8)));
typedef _Float16 half4   __attribute__((ext_vector_type(4)));
typedef float    floatx4 __attribute__((ext_vector_type(4)));

// async global->LDS, 16B per lane; LDS dest is wave-uniform base + lane*16
__device__ __forceinline__ void gload_lds16(const _Float16* g, _Float16* l) {
    __builtin_amdgcn_global_load_lds(
        (const __attribute__((address_space(1))) unsigned int*)g,
        (__attribute__((address_space(3)))       unsigned int*)l,
        16, 0, 0);
}

// ---------------------------------------------------------------------------
// prep: fused  (a) x fp32->f16 flat   [blocks 0..4095]
//              (b) Wqkv^T -> f16      [blocks 4096..7167]
//              (c) Wout^T -> f16      [blocks 7168..8191]
// ---------------------------------------------------------------------------
__global__ __launch_bounds__(256) void prep(
    const float* __restrict__ x, const float* __restrict__ Wqkv,
    const float* __restrict__ Wout,
    _Float16* __restrict__ Xh, _Float16* __restrict__ Wqkt,
    _Float16* __restrict__ Wot)
{
    __shared__ float T[32][33];
    const int b = blockIdx.x;
    if (b < 4096) {
        int i = (b*256 + (int)threadIdx.x)*8;
        float4 a0 = *(const float4*)(x + i);
        float4 a1 = *(const float4*)(x + i + 4);
        half8 h;
        h[0]=(_Float16)a0.x; h[1]=(_Float16)a0.y; h[2]=(_Float16)a0.z; h[3]=(_Float16)a0.w;
        h[4]=(_Float16)a1.x; h[5]=(_Float16)a1.y; h[6]=(_Float16)a1.z; h[7]=(_Float16)a1.w;
        *(half8*)(Xh + i) = h;
        return;
    }
    const float* in; _Float16* out; int C, bx, by;
    if (b < 4096 + 3072) {
        int bb = b - 4096; in = Wqkv; out = Wqkt; C = 3072; bx = bb % 96; by = bb / 96;
    } else {
        int bb = b - 7168; in = Wout; out = Wot;  C = 1024; bx = bb & 31; by = bb >> 5;
    }
    const int tx = threadIdx.x & 31, ty = threadIdx.x >> 5;
#pragma unroll
    for (int i = 0; i < 4; ++i)
        T[ty + i*8][tx] = in[(size_t)(by*32 + ty + i*8)*C + bx*32 + tx];
    __syncthreads();
#pragma unroll
    for (int i = 0; i < 4; ++i)
        out[(size_t)(bx*32 + ty + i*8)*1024 + by*32 + tx] = (_Float16)T[tx][ty + i*8];
}

// ---------------------------------------------------------------------------
// gemm1_qkv: qkv = Xh(8192x1024) @ Wqkt^T, RoPE fused in epilogue.
// m97-style core (128x128, BK=32, global_load_lds). C-layout lanes (l, l^1)
// hold the RoPE pair (dim, dim^1): one shfl_xor rotates in fp32 registers.
// q (pre-scaled 1/8*log2e) -> qw[bh][s][d]; k -> kw; v (no rope) -> vrow.
// ---------------------------------------------------------------------------
__global__ __launch_bounds__(256) void gemm1_qkv(
    const _Float16* __restrict__ A, const _Float16* __restrict__ Bt,
    _Float16* __restrict__ qw, _Float16* __restrict__ kw,
    _Float16* __restrict__ vrow)
{
    __shared__ _Float16 As[128*32];
    __shared__ _Float16 Bs[128*32];
    const int bx = blockIdx.x;               // 0..23 (t = bx>>3)
    const int tid = threadIdx.x;
    const int w = tid >> 6, lane = tid & 63, quad = lane >> 4, l = lane & 15;
    const int wm = (w & 1)*64, wn = (w >> 1)*64;
    const int m0 = blockIdx.y*128, n0 = bx*128;

    const _Float16* a0 = A  + (size_t)(m0 + w*32      + (lane>>2))*DMODEL + (lane&3)*8;
    const _Float16* a1 = A  + (size_t)(m0 + w*32 + 16 + (lane>>2))*DMODEL + (lane&3)*8;
    const _Float16* b0 = Bt + (size_t)(n0 + w*32      + (lane>>2))*DMODEL + (lane&3)*8;
    const _Float16* b1 = Bt + (size_t)(n0 + w*32 + 16 + (lane>>2))*DMODEL + (lane&3)*8;
    _Float16* lA0 = As + w*1024;
    _Float16* lA1 = As + w*1024 + 512;
    _Float16* lB0 = Bs + w*1024;
    _Float16* lB1 = Bs + w*1024 + 512;

    floatx4 acc[4][4];
#pragma unroll
    for (int i = 0; i < 4; ++i)
#pragma unroll
        for (int j = 0; j < 4; ++j)
#pragma unroll
            for (int r = 0; r < 4; ++r) acc[i][j][r] = 0.f;

    for (int k0 = 0; k0 < DMODEL; k0 += 32) {
        __syncthreads();
        gload_lds16(a0, lA0); gload_lds16(a1, lA1);
        gload_lds16(b0, lB0); gload_lds16(b1, lB1);
        a0 += 32; a1 += 32; b0 += 32; b1 += 32;
        __syncthreads();
        half8 bf[4];
#pragma unroll
        for (int nt = 0; nt < 4; ++nt)
            bf[nt] = *(half8*)&Bs[(wn + nt*16 + l)*32 + quad*8];
#pragma unroll
        for (int mt = 0; mt < 4; ++mt) {
            half8 af = *(half8*)&As[(wm + mt*16 + l)*32 + quad*8];
#pragma unroll
            for (int nt = 0; nt < 4; ++nt)
                acc[mt][nt] = __builtin_amdgcn_mfma_f32_16x16x32_f16(af, bf[nt], acc[mt][nt], 0, 0, 0);
        }
    }

    // epilogue: row = m0+wm+mt*16+quad*4+r, col = n0+wn+nt*16+l
    // dim = nt*16+l (wave-uniform head), s within one bt per block.
    const int t    = bx >> 3;                     // 0 q, 1 k, 2 v
    const int head = ((n0 + wn) >> 6) & 15;
    const int bt   = m0 >> 10;
    const int sbase = (m0 & 1023) + wm;
    _Float16* obase = ((t == 0) ? qw : (t == 1) ? kw : vrow)
                      + (size_t)(bt*NH + head)*HS;
    if (t < 2) {
        const float osc = (t == 0) ? 0.125f*LOG2E : 1.0f;
        float bgi[4];
#pragma unroll
        for (int nt = 0; nt < 4; ++nt) {
            int pg = nt*8 + (l >> 1);             // pair index 0..31
            int gi = (pg < 16) ? pg : pg - 16;
            bgi[nt] = (1.0f + gi*(127.0f/15.0f))*PI_F;
        }
#pragma unroll
        for (int mt = 0; mt < 4; ++mt)
#pragma unroll
            for (int r = 0; r < 4; ++r) {
                int s  = sbase + mt*16 + quad*4 + r;
                int hp = s >> 5, wp = s & 31;
                float ph = -1.0f + hp*(2.0f/31.0f);
                float pw = -1.0f + wp*(2.0f/31.0f);
#pragma unroll
                for (int nt = 0; nt < 4; ++nt) {
                    float v  = acc[mt][nt][r];
                    float v2 = __shfl_xor(v, 1);  // partner dim^1
                    float pos = (nt < 2) ? ph : pw;
                    float sn, cs;
                    sincosf(pos*bgi[nt], &sn, &cs);
                    float o = (l & 1) ? (v*cs + v2*sn) : (v*cs - v2*sn);
                    obase[(size_t)s*DH + nt*16 + l] = (_Float16)(o*osc);
                }
            }
    } else {
#pragma unroll
        for (int mt = 0; mt < 4; ++mt)
#pragma unroll
            for (int r = 0; r < 4; ++r) {
                int s = sbase + mt*16 + quad*4 + r;
#pragma unroll
                for (int nt = 0; nt < 4; ++nt)
                    obase[(size_t)s*DH + nt*16 + l] = (_Float16)acc[mt][nt][r];
            }
    }
}

// ---------------------------------------------------------------------------
// v_tr: vrow[bh][s][d] -> vt[bh][d][s], 32x32 ushort tiles (conflict-free).
// ---------------------------------------------------------------------------
__global__ __launch_bounds__(256) void v_tr(
    const _Float16* __restrict__ vrow, _Float16* __restrict__ vt)
{
    __shared__ unsigned short T[32][33];
    const int bh = blockIdx.y;
    const int td = blockIdx.x & 1;        // d-tile 0..1
    const int ts = blockIdx.x >> 1;       // s-tile 0..31
    const int tx = threadIdx.x & 31, ty = threadIdx.x >> 5;
    const unsigned short* src = (const unsigned short*)(vrow + (size_t)bh*HS);
    unsigned short*       dst = (unsigned short*)(vt + (size_t)bh*HS);
#pragma unroll
    for (int i = 0; i < 4; ++i)
        T[ty + i*8][tx] = src[(size_t)(ts*32 + ty + i*8)*DH + td*32 + tx];
    __syncthreads();
#pragma unroll
    for (int i = 0; i < 4; ++i)
        dst[(size_t)(td*32 + ty + i*8)*SEQ + ts*32 + tx] = T[tx][ty + i*8];
}

// ---------------------------------------------------------------------------
// Flash attention v4 (round-6 verified): BQ=128/block, 4 waves x 2 q-tiles,
// double-buffered K/V LDS, no running max, S^T = K.Q^T, P via wave-private LDS.
// ---------------------------------------------------------------------------
#define BC  64
#define LDH 68

__global__ __launch_bounds__(256) void attn_mfma(
    const _Float16* __restrict__ qw, const _Float16* __restrict__ kw,
    const _Float16* __restrict__ vt, _Float16* __restrict__ om)
{
    const int qc = blockIdx.x;    // 0..7
    const int bh = blockIdx.y;    // 0..127
    const int tid  = threadIdx.x;
    const int w    = tid >> 6;
    const int lane = tid & 63;
    const int quad = lane >> 4;
    const int l    = lane & 15;

    __shared__ _Float16 Ks[2][BC][LDH];
    __shared__ _Float16 Vs[2][DH][LDH];
    __shared__ _Float16 Ps[4][32][LDH];
    __shared__ float    Ls[4][32];

    const _Float16* qp = qw + (size_t)bh*HS + (size_t)(qc*128 + w*32)*DH;
    const _Float16* kp = kw + (size_t)bh*HS;
    const _Float16* vp = vt + (size_t)bh*HS;   // [d][1024]

    half8 qf[2][2];
#pragma unroll
    for (int qt = 0; qt < 2; ++qt) {
        qf[qt][0] = *(const half8*)(qp + (size_t)(qt*16 + l)*DH + quad*8);
        qf[qt][1] = *(const half8*)(qp + (size_t)(qt*16 + l)*DH + quad*8 + 32);
    }

    const int rs = tid >> 3;           // 0..31
    const int cs = (tid & 7)*8;        // 0..56

    half8 kr0 = *(const half8*)(kp + (size_t)rs*DH + cs);
    half8 kr1 = *(const half8*)(kp + (size_t)(rs+32)*DH + cs);
    half8 vr0 = *(const half8*)(vp + (size_t)rs*SEQ + cs);
    half8 vr1 = *(const half8*)(vp + (size_t)(rs+32)*SEQ + cs);
    *(half8*)&Ks[0][rs][cs]    = kr0;
    *(half8*)&Ks[0][rs+32][cs] = kr1;
    *(half8*)&Vs[0][rs][cs]    = vr0;
    *(half8*)&Vs[0][rs+32][cs] = vr1;

    floatx4 Of[2][4];
#pragma unroll
    for (int qt = 0; qt < 2; ++qt)
#pragma unroll
        for (int dt = 0; dt < 4; ++dt)
#pragma unroll
            for (int r = 0; r < 4; ++r) Of[qt][dt][r] = 0.f;
    float lsum[2] = {0.f, 0.f};

    __syncthreads();

    for (int kc = 0; kc < SEQ/BC; ++kc) {
        const int cur = kc & 1;
        if (kc < SEQ/BC - 1) {
            const _Float16* kn = kp + (size_t)(kc+1)*BC*DH;
            const _Float16* vn = vp + (size_t)(kc+1)*BC;
            kr0 = *(const half8*)(kn + (size_t)rs*DH + cs);
            kr1 = *(const half8*)(kn + (size_t)(rs+32)*DH + cs);
            vr0 = *(const half8*)(vn + (size_t)rs*SEQ + cs);
            vr1 = *(const half8*)(vn + (size_t)(rs+32)*SEQ + cs);
        }

        floatx4 Sf[2][4];
#pragma unroll
        for (int kg = 0; kg < 4; ++kg) {
            half8 af0 = *(half8*)&Ks[cur][kg*16 + l][quad*8];
            half8 af1 = *(half8*)&Ks[cur][kg*16 + l][quad*8 + 32];
#pragma unroll
            for (int qt = 0; qt < 2; ++qt) {
                floatx4 a;
#pragma unroll
                for (int r = 0; r < 4; ++r) a[r] = 0.f;
                a = __builtin_amdgcn_mfma_f32_16x16x32_f16(af0, qf[qt][0], a, 0, 0, 0);
                a = __builtin_amdgcn_mfma_f32_16x16x32_f16(af1, qf[qt][1], a, 0, 0, 0);
                Sf[qt][kg] = a;
            }
        }
#pragma unroll
        for (int qt = 0; qt < 2; ++qt)
#pragma unroll
            for (int kg = 0; kg < 4; ++kg) {
                half4 p4;
#pragma unroll
                for (int r = 0; r < 4; ++r) {
                    float p = __builtin_amdgcn_exp2f(Sf[qt][kg][r]);
                    lsum[qt] += p;
                    p4[r] = (_Float16)p;
                }
                *(half4*)&Ps[w][qt*16 + l][kg*16 + quad*4] = p4;
            }
        half8 pa[2][2];
#pragma unroll
        for (int qt = 0; qt < 2; ++qt) {
            pa[qt][0] = *(half8*)&Ps[w][qt*16 + l][quad*8];
            pa[qt][1] = *(half8*)&Ps[w][qt*16 + l][quad*8 + 32];
        }
#pragma unroll
        for (int dt = 0; dt < 4; ++dt) {
            half8 vb0 = *(half8*)&Vs[cur][dt*16 + l][quad*8];
            half8 vb1 = *(half8*)&Vs[cur][dt*16 + l][quad*8 + 32];
#pragma unroll
            for (int qt = 0; qt < 2; ++qt) {
                Of[qt][dt] = __builtin_amdgcn_mfma_f32_16x16x32_f16(pa[qt][0], vb0, Of[qt][dt], 0, 0, 0);
                Of[qt][dt] = __builtin_amdgcn_mfma_f32_16x16x32_f16(pa[qt][1], vb1, Of[qt][dt], 0, 0, 0);
            }
        }

        if (kc < SEQ/BC - 1) {
            *(half8*)&Ks[1-cur][rs][cs]    = kr0;
            *(half8*)&Ks[1-cur][rs+32][cs] = kr1;
            *(half8*)&Vs[1-cur][rs][cs]    = vr0;
            *(half8*)&Vs[1-cur][rs+32][cs] = vr1;
        }
        __syncthreads();
    }

#pragma unroll
    for (int qt = 0; qt < 2; ++qt) {
        lsum[qt] += __shfl_xor(lsum[qt], 16);
        lsum[qt] += __shfl_xor(lsum[qt], 32);
        if (quad == 0) Ls[w][qt*16 + l] = lsum[qt];
    }
    const int bt = bh >> 4, head = bh & 15;
    _Float16* opf = om + (size_t)(bt*SEQ + qc*128 + w*32)*DMODEL + head*DH;
#pragma unroll
    for (int qt = 0; qt < 2; ++qt) {
        float inv[4];
#pragma unroll
        for (int r = 0; r < 4; ++r) inv[r] = 1.0f / Ls[w][qt*16 + quad*4 + r];
#pragma unroll
        for (int dt = 0; dt < 4; ++dt)
#pragma unroll
            for (int r = 0; r < 4; ++r)
                opf[(size_t)(qt*16 + quad*4 + r)*DMODEL + dt*16 + l] =
                    (_Float16)(Of[qt][dt][r]*inv[r]);
    }
}

// ---------------------------------------------------------------------------
// gemm2: out = om(8192x1024) @ Wot^T + bias, fp32 out (m97-style core)
// ---------------------------------------------------------------------------
__global__ __launch_bounds__(256) void gemm2_f16(
    const _Float16* __restrict__ A, const _Float16* __restrict__ Bt,
    const float* __restrict__ bias, float* __restrict__ C, int M, int N, int K)
{
    __shared__ _Float16 As[128*32];
    __shared__ _Float16 Bs[128*32];
    const int tid = threadIdx.x;
    const int w = tid >> 6, lane = tid & 63, quad = lane >> 4, l = lane & 15;
    const int wm = (w & 1)*64, wn = (w >> 1)*64;
    const int m0 = blockIdx.y*128, n0 = blockIdx.x*128;

    const _Float16* a0 = A  + (size_t)(m0 + w*32      + (lane>>2))*K + (lane&3)*8;
    const _Float16* a1 = A  + (size_t)(m0 + w*32 + 16 + (lane>>2))*K + (lane&3)*8;
    const _Float16* b0 = Bt + (size_t)(n0 + w*32      + (lane>>2))*K + (lane&3)*8;
    const _Float16* b1 = Bt + (size_t)(n0 + w*32 + 16 + (lane>>2))*K + (lane&3)*8;
    _Float16* lA0 = As + w*1024;
    _Float16* lA1 = As + w*1024 + 512;
    _Float16* lB0 = Bs + w*1024;
    _Float16* lB1 = Bs + w*1024 + 512;

    floatx4 acc[4][4];
#pragma unroll
    for (int i = 0; i < 4; ++i)
#pragma unroll
        for (int j = 0; j < 4; ++j)
#pragma unroll
            for (int r = 0; r < 4; ++r) acc[i][j][r] = 0.f;

    for (int k0 = 0; k0 < K; k0 += 32) {
        __syncthreads();
        gload_lds16(a0, lA0); gload_lds16(a1, lA1);
        gload_lds16(b0, lB0); gload_lds16(b1, lB1);
        a0 += 32; a1 += 32; b0 += 32; b1 += 32;
        __syncthreads();
        half8 bf[4];
#pragma unroll
        for (int nt = 0; nt < 4; ++nt)
            bf[nt] = *(half8*)&Bs[(wn + nt*16 + l)*32 + quad*8];
#pragma unroll
        for (int mt = 0; mt < 4; ++mt) {
            half8 af = *(half8*)&As[(wm + mt*16 + l)*32 + quad*8];
#pragma unroll
            for (int nt = 0; nt < 4; ++nt)
                acc[mt][nt] = __builtin_amdgcn_mfma_f32_16x16x32_f16(af, bf[nt], acc[mt][nt], 0, 0, 0);
        }
    }
#pragma unroll
    for (int mt = 0; mt < 4; ++mt)
#pragma unroll
        for (int r = 0; r < 4; ++r) {
            size_t row = m0 + wm + mt*16 + quad*4 + r;
#pragma unroll
            for (int nt = 0; nt < 4; ++nt) {
                int col = n0 + wn + nt*16 + l;
                C[row*N + col] = acc[mt][nt][r] + bias[col];
            }
        }
}

// ---------------------------------------------------------------------------
extern "C" void kernel_launch(void* const* d_in, const int* in_sizes, int n_in,
                              void* d_out, int out_size, void* d_ws, size_t ws_size,
                              hipStream_t stream)
{
    const float* x    = (const float*)d_in[0];
    const float* Wqkv = (const float*)d_in[1];
    const float* Wout = (const float*)d_in[2];
    const float* bout = (const float*)d_in[3];
    float* out = (float*)d_out;

    _Float16* ws   = (_Float16*)d_ws;
    _Float16* Xh   = ws;                  //  8388608
    _Float16* Wqkt = ws + 8388608;        //  3145728 [3072][1024]
    _Float16* Wot  = ws + 11534336;       //  1048576 [1024][1024]
    _Float16* qw   = ws + 12582912;       //  8388608 [bh][s][d]
    _Float16* kw   = ws + 20971520;       //  8388608
    _Float16* vrow = ws + 29360128;       //  8388608 [bh][s][d]
    _Float16* vt   = ws + 37748736;       //  8388608 [bh][d][s]
    _Float16* om   = ws + 46137344;       //  8388608 [bt*s][h*d] (end 104 MiB)

    hipLaunchKernelGGL(prep, dim3(8192), dim3(256), 0, stream,
                       x, Wqkv, Wout, Xh, Wqkt, Wot);
    hipLaunchKernelGGL(gemm1_qkv, dim3(24, 64), dim3(256), 0, stream,
                       Xh, Wqkt, qw, kw, vrow);
    hipLaunchKernelGGL(v_tr, dim3(64, 128), dim3(256), 0, stream,
                       vrow, vt);
    hipLaunchKernelGGL(attn_mfma, dim3(8, 128), dim3(256), 0, stream,
                       qw, kw, vt, om);
    hipLaunchKernelGGL(gemm2_f16, dim3(8, 64), dim3(256), 0, stream,
                       om, Wot, bout, out, 8192, DMODEL, DMODEL);
}